// Round 1
// baseline (988.184 us; speedup 1.0000x reference)
//
#include <hip/hip_runtime.h>

// SuppAlignLayer: 4-level ROI Align, B=2, C=256, N=512 boxes/batch, OUT=7, SR=2.
// Output per level: (1024, 256, 7, 7) fp32, levels concatenated flat.
//
// Strategy: 1 block per (roi, level). 196 threads precompute the 14x14 sample
// grid's bilinear metadata (4 flat offsets + 4 weights, validity & 0.25 mean
// factor folded in) into LDS once; all 256 channels then reuse it.
// Item loop (item = c*49 + bin) gives perfectly coalesced output stores.

#define OUTSZ 7
#define NSAMP 196        // 49 bins * 4 subsamples
#define ITEMS 12544      // 256 channels * 49 bins
#define ROI_STRIDE 12544u
#define LVL_STRIDE 12845056u   // 1024 * 12544

__global__ __launch_bounds__(256)
void roi_align_all_levels(const float* __restrict__ f0,
                          const float* __restrict__ f1,
                          const float* __restrict__ f2,
                          const float* __restrict__ f3,
                          const float* __restrict__ boxes,
                          float* __restrict__ out)
{
    __shared__ int4   sIdx[NSAMP];
    __shared__ float4 sW[NSAMP];

    const int r   = blockIdx.x;      // roi index 0..1023
    const int lvl = blockIdx.y;      // level 0..3
    const int t   = threadIdx.x;

    int H, W; float scale; const float* feat;
    switch (lvl) {
      case 0:  H = 200; W = 304; scale = 0.25f;    feat = f0; break;
      case 1:  H = 100; W = 152; scale = 0.125f;   feat = f1; break;
      case 2:  H = 50;  W = 76;  scale = 0.0625f;  feat = f2; break;
      default: H = 25;  W = 38;  scale = 0.03125f; feat = f3; break;
    }
    const unsigned HW = (unsigned)(H * W);
    const int b = r >> 9;            // batch = roi / 512

    if (t < NSAMP) {
        const float bx1 = boxes[r * 4 + 0] * scale;
        const float by1 = boxes[r * 4 + 1] * scale;
        const float bx2 = boxes[r * 4 + 2] * scale;
        const float by2 = boxes[r * 4 + 3] * scale;
        const float rw  = fmaxf(bx2 - bx1, 1.0f);
        const float rh  = fmaxf(by2 - by1, 1.0f);

        // sample layout: m = bin*4 + sub, sub = iy*2 + ix
        const int bin = t >> 2, sub = t & 3;
        const int ph = bin / 7, pw = bin % 7;
        const int ky = 2 * ph + (sub >> 1);
        const int kx = 2 * pw + (sub & 1);

        const float gy = ((float)ky + 0.5f) * 0.5f;   // (k+0.5)/SR
        const float gx = ((float)kx + 0.5f) * 0.5f;
        const float ys = by1 + (rh / 7.0f) * gy;
        const float xs = bx1 + (rw / 7.0f) * gx;

        const float Hf = (float)H, Wf = (float)W;
        const bool vy = (ys >= -1.0f) && (ys <= Hf);
        const bool vx = (xs >= -1.0f) && (xs <= Wf);

        const float yc = fminf(fmaxf(ys, 0.0f), Hf - 1.0f);
        const float xc = fminf(fmaxf(xs, 0.0f), Wf - 1.0f);
        const int y0 = (int)yc;            // yc >= 0 -> trunc == floor
        const int x0 = (int)xc;
        const int y1i = min(y0 + 1, H - 1);
        const int x1i = min(x0 + 1, W - 1);
        const float ly = yc - (float)y0, lx = xc - (float)x0;
        const float hy = 1.0f - ly, hx = 1.0f - lx;

        const float vm = (vy && vx) ? 0.25f : 0.0f;   // fold mean over 2x2

        sIdx[t] = make_int4(y0 * W + x0, y0 * W + x1i, y1i * W + x0, y1i * W + x1i);
        sW[t]   = make_float4(hy * hx * vm, hy * lx * vm, ly * hx * vm, ly * lx * vm);
    }
    __syncthreads();

    const float* base = feat + (size_t)b * (size_t)(256u * HW);
    float* o = out + (size_t)lvl * LVL_STRIDE + (size_t)r * ROI_STRIDE;

    #pragma unroll 1
    for (int i = 0; i < 49; ++i) {
        const int item = i * 256 + t;
        const unsigned c = (unsigned)item / 49u;      // magic-mul div
        const int bin = item - (int)c * 49;
        const float* p = base + (size_t)c * HW;

        float acc = 0.0f;
        #pragma unroll
        for (int sub = 0; sub < 4; ++sub) {
            const int4   d  = sIdx[bin * 4 + sub];
            const float4 wt = sW[bin * 4 + sub];
            acc += p[d.x] * wt.x;
            acc += p[d.y] * wt.y;
            acc += p[d.z] * wt.z;
            acc += p[d.w] * wt.w;
        }
        o[item] = acc;
    }
}

extern "C" void kernel_launch(void* const* d_in, const int* in_sizes, int n_in,
                              void* d_out, int out_size, void* d_ws, size_t ws_size,
                              hipStream_t stream) {
    const float* f0    = (const float*)d_in[0];
    const float* f1    = (const float*)d_in[1];
    const float* f2    = (const float*)d_in[2];
    const float* f3    = (const float*)d_in[3];
    const float* boxes = (const float*)d_in[4];
    float* out = (float*)d_out;

    dim3 grid(1024, 4);
    roi_align_all_levels<<<grid, 256, 0, stream>>>(f0, f1, f2, f3, boxes, out);
}